// Round 8
// baseline (342.173 us; speedup 1.0000x reference)
//
#include <hip/hip_runtime.h>
#include <hip/hip_bf16.h>
#include <math.h>

#define NQ 8192      // queries (columns of the transposed cost)
#define NC 32000     // classes
#define NT 128       // targets (rows of the transposed cost)
#define SROW 256     // kept (smallest) sorted entries per row
#define SLOTC 128    // assigned-column slots cached in LDS (all of them)

typedef float v4f __attribute__((ext_vector_type(4)));

// ---------------------------------------------------------------------------
// Kernel A: per-row softmax stats + cost build in BOTH orientations.
// ---------------------------------------------------------------------------
__global__ __launch_bounds__(256) void build_cost(
    const float* __restrict__ outp, const int* __restrict__ tgt,
    float* __restrict__ C, float* __restrict__ Ccol)
{
  const int row = blockIdx.x;
  const int tid = threadIdx.x;
  const float* x = outp + (size_t)row * NC;

  float m = -INFINITY;
  double s = 0.0;
  const v4f* x4 = (const v4f*)x;
  for (int k = tid; k < NC / 4; k += 256) {
    v4f v = __builtin_nontemporal_load(x4 + k);
    float mv = fmaxf(fmaxf(v.x, v.y), fmaxf(v.z, v.w));
    if (mv > m) { s *= exp((double)(m - mv)); m = mv; }
    s += (double)__expf(v.x - m) + (double)__expf(v.y - m)
       + (double)__expf(v.z - m) + (double)__expf(v.w - m);
  }

  __shared__ float  lsm[4];
  __shared__ double lss[4];
  __shared__ float  bM;
  __shared__ double bS;

  float wm = m;
  #pragma unroll
  for (int off = 32; off; off >>= 1) wm = fmaxf(wm, __shfl_xor(wm, off));
  const int wid = tid >> 6;
  if ((tid & 63) == 0) lsm[wid] = wm;
  __syncthreads();
  if (tid == 0) bM = fmaxf(fmaxf(lsm[0], lsm[1]), fmaxf(lsm[2], lsm[3]));
  __syncthreads();
  const float M = bM;

  double s2 = s * exp((double)m - (double)M);
  #pragma unroll
  for (int off = 32; off; off >>= 1) s2 += __shfl_xor(s2, off);
  if ((tid & 63) == 0) lss[wid] = s2;
  __syncthreads();
  if (tid == 0) bS = lss[0] + lss[1] + lss[2] + lss[3];
  __syncthreads();
  const double S = bS;

  if (tid < NT) {
    const int c = tgt[tid];
    const double p = exp((double)x[c] - (double)M) / S;
    const float cv = 1.0f - (float)p;
    C[(size_t)tid * NQ + row]    = cv;
    Ccol[(size_t)row * NT + tid] = cv;
  }
}

// ---------------------------------------------------------------------------
// Kernel B1: per (row, 1024-part) top-256 sorted ascending by (cost_bits, j).
// ---------------------------------------------------------------------------
__global__ __launch_bounds__(256) void select_part(
    const float* __restrict__ C, unsigned long long* __restrict__ S1)
{
  __shared__ unsigned long long key[1024];
  const int part = blockIdx.x, t = blockIdx.y, tid = threadIdx.x;
  const float* crow = C + (size_t)t * NQ + part * 1024;
  for (int i = tid; i < 1024; i += 256)
    key[i] = ((unsigned long long)__float_as_uint(crow[i]) << 32)
           | (unsigned)(part * 1024 + i);

  for (int k = 2; k <= 256; k <<= 1)
    for (int jj = k >> 1; jj > 0; jj >>= 1) {
      __syncthreads();
      for (int w = tid; w < 512; w += 256) {
        const int i1 = ((w & ~(jj - 1)) << 1) | (w & (jj - 1));
        const int i2 = i1 | jj;
        const bool up = (((i1 & 255) & k) == 0);
        const unsigned long long a = key[i1], b = key[i2];
        if ((a > b) == up) { key[i1] = b; key[i2] = a; }
      }
    }

  for (int step = 1; step < 4; step <<= 1) {
    const int npairs = 2 / step;
    __syncthreads();
    for (int w = tid; w < npairs * 256; w += 256) {
      const int p = w >> 8, i = w & 255;
      const int a = ((p * 2 * step) << 8) + i;
      const int b = ((p * 2 * step + step) << 8) + 255 - i;
      const unsigned long long ka = key[a], kb = key[b];
      if (ka > kb) key[a] = kb;
    }
    for (int jj = 128; jj > 0; jj >>= 1) {
      __syncthreads();
      for (int w = tid; w < npairs * 128; w += 256) {
        const int p = w >> 7, q = w & 127;
        const int base = (p * 2 * step) << 8;
        const int i1 = base + (((q & ~(jj - 1)) << 1) | (q & (jj - 1)));
        const int i2 = i1 | jj;
        const unsigned long long a = key[i1], b = key[i2];
        if (a > b) { key[i1] = b; key[i2] = a; }
      }
    }
  }
  __syncthreads();
  S1[((size_t)t * 8 + part) * 256 + tid] = key[tid];
}

// ---------------------------------------------------------------------------
// Kernel B2: merge 8 sorted top-256 lists -> top-256 per row (3 rounds).
// ---------------------------------------------------------------------------
__global__ __launch_bounds__(256) void select_merge(
    const unsigned long long* __restrict__ S1, unsigned long long* __restrict__ S)
{
  __shared__ unsigned long long key[2048];
  const int t = blockIdx.x, tid = threadIdx.x;
  for (int i = tid; i < 2048; i += 256) key[i] = S1[(size_t)t * 2048 + i];

  for (int step = 1; step < 8; step <<= 1) {
    const int npairs = 4 / step;
    __syncthreads();
    for (int w = tid; w < npairs * 256; w += 256) {
      const int p = w >> 8, i = w & 255;
      const int a = ((p * 2 * step) << 8) + i;
      const int b = ((p * 2 * step + step) << 8) + 255 - i;
      const unsigned long long ka = key[a], kb = key[b];
      if (ka > kb) key[a] = kb;
    }
    for (int jj = 128; jj > 0; jj >>= 1) {
      __syncthreads();
      for (int w = tid; w < npairs * 128; w += 256) {
        const int p = w >> 7, q = w & 127;
        const int base = (p * 2 * step) << 8;
        const int i1 = base + (((q & ~(jj - 1)) << 1) | (q & (jj - 1)));
        const int i2 = i1 | jj;
        const unsigned long long a = key[i1], b = key[i2];
        if (a > b) { key[i1] = b; key[i2] = a; }
      }
    }
  }
  __syncthreads();
  S[(size_t)t * SROW + tid] = key[tid];
}

// --------------------------- readlane helpers ------------------------------
__device__ __forceinline__ int rl_i32(int v, int l) {
  return __builtin_amdgcn_readlane(v, l);
}
__device__ __forceinline__ double rl_f64(double v, int l) {
  union { double d; int i[2]; } a; a.d = v;
  union { int i[2]; double d; } r;
  r.i[0] = __builtin_amdgcn_readlane(a.i[0], l);
  r.i[1] = __builtin_amdgcn_readlane(a.i[1], l);
  return r.d;
}
__device__ __forceinline__ unsigned long long rl_u64(unsigned long long v, int l) {
  union { unsigned long long q; int i[2]; } a; a.q = v;
  union { int i[2]; unsigned long long q; } r;
  r.i[0] = __builtin_amdgcn_readlane(a.i[0], l);
  r.i[1] = __builtin_amdgcn_readlane(a.i[1], l);
  return r.q;
}

// DPP value-only f64 min step (no NaNs in this kernel; zeros sign-safe).
template <int CTRL>
__device__ __forceinline__ double dpp_min_f64(double cr) {
  union { double d; int i[2]; } a, r;
  a.d = cr;
  r.i[0] = __builtin_amdgcn_update_dpp(0, a.i[0], CTRL, 0xF, 0xF, true);
  r.i[1] = __builtin_amdgcn_update_dpp(0, a.i[1], CTRL, 0xF, 0xF, true);
  return fmin(cr, r.d);
}

// ---------------------------------------------------------------------------
// Kernel C: exact JV LSAP, single wave, barrier-free.
// vs R7: (1) two-level register candidate cache (cand/cand2) — the probe
// ballot yields the first TWO unassigned entries; promotion on invalidation
// is a register move (exact: columns only ever become assigned);
// (2) du[] read-back deferred until after the augment walk so the LDS
// store->load turnaround hides under it.
// Decision semantics identical to the verified R2..R7 solver.
// ---------------------------------------------------------------------------
__global__ __launch_bounds__(64) void lsap_solve(
    const float* __restrict__ Ccol, const unsigned long long* __restrict__ S,
    int* __restrict__ outi)
{
  const int lane = threadIdx.x;

  __shared__ float  Clds[NT][SLOTC];            // 64 KB, [row][(slot+row)&127]
  __shared__ double du[NT];                     // dual-delta routing
  __shared__ unsigned long long abm[NQ / 64];   // assigned bitmap (probe-only)
  __shared__ short col4row_s[NT];               // staging for the final sort

  int    acolA = -1, acolB = -1;     // column of slot (A: slot=lane, B: 64+lane)
  int    arowA = -1, arowB = -1;     // row4col[col]
  int    apathA = -1, apathB = -1;   // path[col]
  double avA = 0.0, avB = 0.0;       // v[col]
  double ashA = 0.0, ashB = 0.0;     // shortest[col]
  double afzA = 0.0, afzB = 0.0;     // shortest frozen at selection
  bool   ascA = false, ascB = false; // SC[col]
  int    nA = 0;

  // lane L owns rows L and 64+L:
  double uA = 0.0, uB = 0.0;                       // u[row]
  int    c4rA = -1, c4rB = -1;                     // col4row[row]
  unsigned long long candA, candB, candA2, candB2; // 1st/2nd unassigned keys
  int    curA, curB, curA2, curB2;                 // their sorted positions

  abm[lane] = 0ull;  abm[64 + lane] = 0ull;
  // pre-seed with each row's two smallest keys (valid: nothing assigned yet)
  candA  = S[(size_t)lane * SROW];
  candA2 = S[(size_t)lane * SROW + 1];
  candB  = S[(size_t)(64 + lane) * SROW];
  candB2 = S[(size_t)(64 + lane) * SROW + 1];
  curA = 0; curA2 = 1; curB = 0; curB2 = 1;

  for (int cur = 0; cur < NT; ++cur) {
    ashA = INFINITY; ashB = INFINITY; ascA = false; ascB = false;
    double ub_r = INFINITY; int ub_j = 0x7fffffff, ub_i = -1;
    int icur = cur; double minval = 0.0;
    int sink = -1, sinkpath = -1;

    while (sink < 0) {
      const double u_i = (icur < 64) ? rl_f64(uA, icur) : rl_f64(uB, icur - 64);
      const bool actA = (lane < nA) && !ascA;
      const bool actB = (64 + lane < nA) && !ascB;
      float cA = 0.f, cB = 0.f;
      if (actA) cA = Clds[icur][(lane + icur) & 127];
      if (actB) cB = Clds[icur][(64 + lane + icur) & 127];

      // --- U-side: register-cached first-unassigned sorted candidate
      unsigned long long kk = (icur < 64) ? rl_u64(candA, icur)
                                          : rl_u64(candB, icur - 64);
      if (kk == 0ull) {   // probe the sorted row (rare: both cache levels dead)
        int pos = (icur < 64) ? rl_i32(curA, icur) : rl_i32(curB, icur - 64);
        unsigned long long kk2 = 0ull; int pos2 = pos;
        for (;;) {
          const unsigned long long k = S[(size_t)icur * SROW + pos + lane];
          const int j = (int)(k & 0xffffffffu);
          const bool asg = (abm[j >> 6] >> (j & 63)) & 1ull;
          const unsigned long long bal = __ballot(!asg);
          if (bal) {
            const int f = __builtin_ctzll(bal);
            kk = rl_u64(k, f);
            const unsigned long long bal2 = bal & (bal - 1);
            if (bal2) {
              const int f2 = __builtin_ctzll(bal2);
              kk2  = rl_u64(k, f2);
              pos2 = pos + f2;
            }
            pos += f;
            break;
          }
          pos += 64;
        }
        if (lane == (icur & 63)) {
          if (icur < 64) { candA = kk; curA = pos; candA2 = kk2; curA2 = pos2; }
          else           { candB = kk; curB = pos; candB2 = kk2; curB2 = pos2; }
        }
      }
      {
        const int    jU = (int)(kk & 0xffffffffu);
        const double cU = (double)__uint_as_float((unsigned)(kk >> 32));
        const double rU = ((minval + cU) - u_i) - 0.0;   // v[j]==0 on U
        if (rU < ub_r || (rU == ub_r && jU < ub_j)) { ub_r = rU; ub_j = jU; ub_i = icur; }
      }

      // --- A-side: update shortest over unscanned assigned columns
      if (actA) {
        const double r = ((minval + (double)cA) - u_i) - avA;
        if (r < ashA) { ashA = r; apathA = icur; }
      }
      if (actB) {
        const double r = ((minval + (double)cB) - u_i) - avB;
        if (r < ashB) { ashB = r; apathB = icur; }
      }
      // value-only min: per-lane pair, DPP within 16-groups, readlane across
      double cr = actA ? ashA : INFINITY;
      if (actB) cr = fmin(cr, ashB);
      cr = dpp_min_f64<0xB1>(cr);    // quad_perm(1,0,3,2)  == xor 1
      cr = dpp_min_f64<0x4E>(cr);    // quad_perm(2,3,0,1)  == xor 2
      cr = dpp_min_f64<0x141>(cr);   // row_half_mirror     == xor 7
      cr = dpp_min_f64<0x140>(cr);   // row_mirror          == xor 15
      cr = fmin(fmin(rl_f64(cr, 0), rl_f64(cr, 16)),
                fmin(rl_f64(cr, 32), rl_f64(cr, 48)));

      // --- recover winning slot (unique match fast path; exact ties rare)
      const bool mA = actA && (ashA == cr);
      const bool mB = actB && (ashB == cr);
      const unsigned long long balA = __ballot(mA);
      const unsigned long long balB = __ballot(mB);
      int ln = -1, isB = 0, cj = 0x7fffffff;
      if (__popcll(balA) + __popcll(balB) == 1) {
        isB = (balA == 0ull);
        ln  = (int)__builtin_ctzll(balA | balB);
        cj  = isB ? rl_i32(acolB, ln) : rl_i32(acolA, ln);
      } else if ((balA | balB) != 0ull) {
        unsigned long long ba = balA;
        while (ba) {
          const int l = (int)__builtin_ctzll(ba); ba &= ba - 1;
          const int c = rl_i32(acolA, l);
          if (c < cj) { cj = c; ln = l; isB = 0; }
        }
        unsigned long long bb = balB;
        while (bb) {
          const int l = (int)__builtin_ctzll(bb); bb &= bb - 1;
          const int c = rl_i32(acolB, l);
          if (c < cj) { cj = c; ln = l; isB = 1; }
        }
      }

      // --- decision (uniform)
      if (cr < ub_r || (cr == ub_r && cj < ub_j)) {
        minval = cr;
        if (lane == ln) {
          if (isB) { ascB = true; afzB = cr; }
          else     { ascA = true; afzA = cr; }
        }
        icur = isB ? rl_i32(arowB, ln) : rl_i32(arowA, ln);
      } else {
        minval = ub_r;
        sink = ub_j; sinkpath = ub_i;
      }
    }

    // --- prefetch sink's cost column (coalesced; hides under duals + walk)
    const int nAold = nA;
    const float fc0 = Ccol[(size_t)sink * NT + lane];
    const float fc1 = Ccol[(size_t)sink * NT + 64 + lane];

    // --- dual updates: write deltas; read-back deferred past the walk
    du[lane] = 0.0; du[64 + lane] = 0.0;
    if (ascA) { du[arowA] = minval - afzA; avA -= (minval - afzA); }
    if (ascB) { du[arowB] = minval - afzB; avB -= (minval - afzB); }

    // --- augment along the alternating path
    {
      int j = sink, i = sinkpath;
      if (lane == (nAold & 63)) {            // append sink as new slot
        if (nAold < 64) { acolA = sink; avA = 0.0; arowA = i; }
        else            { acolB = sink; avB = 0.0; arowB = i; }
      }
      if (lane == 0) abm[sink >> 6] |= 1ull << (sink & 63);
      nA = nAold + 1;
      for (;;) {
        const int jn = (i < 64) ? rl_i32(c4rA, i) : rl_i32(c4rB, i - 64);
        if (lane == (i & 63)) { if (i < 64) c4rA = j; else c4rB = j; }
        if (i == cur) break;
        j = jn;
        const bool hA = (acolA == j);
        const bool hB = (acolB == j);
        const unsigned long long bal = __ballot(hA || hB);
        const int ln2 = (int)__builtin_ctzll(bal);
        const int isB2 = rl_i32(hB ? 1 : 0, ln2);
        const int ni = isB2 ? rl_i32(apathB, ln2) : rl_i32(apathA, ln2);
        if (lane == ln2) { if (isB2) arowB = ni; else arowA = ni; }
        i = ni;
      }
    }

    // --- deferred dual read-back (du stores have drained under the walk)
    uA += du[lane];
    uB += du[64 + lane];
    if (lane == (cur & 63)) { if (cur < 64) uA += minval; else uB += minval; }

    // --- cand invalidation with register promotion (exact, see header)
    if ((int)(candA2 & 0xffffffffu) == sink) candA2 = 0ull;
    if ((int)(candB2 & 0xffffffffu) == sink) candB2 = 0ull;
    if ((int)(candA  & 0xffffffffu) == sink) {
      candA = candA2; curA = curA2; candA2 = 0ull;
    }
    if ((int)(candB  & 0xffffffffu) == sink) {
      candB = candB2; curB = curB2; candB2 = 0ull;
    }

    // --- land the prefetched column into swizzled Clds (conflict-free)
    Clds[lane][(nAold + lane) & 127]           = fc0;
    Clds[64 + lane][(nAold + 64 + lane) & 127] = fc1;
  }

  // output: rows = col4row (query idx), cols = arange(NT), sorted by query idx
  col4row_s[lane]      = (short)c4rA;
  col4row_s[64 + lane] = (short)c4rB;
  for (int t = lane; t < NT; t += 64) {
    const int q = col4row_s[t];
    int rank = 0;
    for (int k = 0; k < NT; ++k) rank += (col4row_s[k] < q);
    outi[rank]      = q;
    outi[NT + rank] = t;
  }
}

extern "C" void kernel_launch(void* const* d_in, const int* in_sizes, int n_in,
                              void* d_out, int out_size, void* d_ws, size_t ws_size,
                              hipStream_t stream) {
  (void)in_sizes; (void)n_in; (void)out_size; (void)ws_size;
  const float* outputs = (const float*)d_in[0];
  const int*   targets = (const int*)d_in[1];
  char* ws = (char*)d_ws;
  float* C    = (float*)ws;                                  // 4 MB
  float* Ccol = (float*)(ws + (size_t)NT * NQ * 4);          // 4 MB
  unsigned long long* S1 =
      (unsigned long long*)(ws + (size_t)NT * NQ * 8);       // 2 MB
  unsigned long long* S =
      (unsigned long long*)(ws + (size_t)NT * NQ * 8 + (size_t)NT * 8 * 256 * 8);
  int* out = (int*)d_out;

  build_cost<<<NQ, 256, 0, stream>>>(outputs, targets, C, Ccol);
  select_part<<<dim3(8, NT), 256, 0, stream>>>(C, S1);
  select_merge<<<NT, 256, 0, stream>>>(S1, S);
  lsap_solve<<<1, 64, 0, stream>>>(Ccol, S, out);
}

// Round 9
// 337.565 us; speedup vs baseline: 1.0137x; 1.0137x over previous
//
#include <hip/hip_runtime.h>
#include <hip/hip_bf16.h>
#include <math.h>

#define NQ 8192      // queries (columns of the transposed cost)
#define NC 32000     // classes
#define NT 128       // targets (rows of the transposed cost)
#define SROW 256     // kept (smallest) sorted entries per row
#define SLOTC 128    // assigned-column slots cached in LDS (all of them)

typedef float v4f __attribute__((ext_vector_type(4)));

// ---------------------------------------------------------------------------
// Kernel A: per-row softmax stats + cost build in BOTH orientations.
// ---------------------------------------------------------------------------
__global__ __launch_bounds__(256) void build_cost(
    const float* __restrict__ outp, const int* __restrict__ tgt,
    float* __restrict__ C, float* __restrict__ Ccol)
{
  const int row = blockIdx.x;
  const int tid = threadIdx.x;
  const float* x = outp + (size_t)row * NC;

  float m = -INFINITY;
  double s = 0.0;
  const v4f* x4 = (const v4f*)x;
  for (int k = tid; k < NC / 4; k += 256) {
    v4f v = __builtin_nontemporal_load(x4 + k);
    float mv = fmaxf(fmaxf(v.x, v.y), fmaxf(v.z, v.w));
    if (mv > m) { s *= exp((double)(m - mv)); m = mv; }
    s += (double)__expf(v.x - m) + (double)__expf(v.y - m)
       + (double)__expf(v.z - m) + (double)__expf(v.w - m);
  }

  __shared__ float  lsm[4];
  __shared__ double lss[4];
  __shared__ float  bM;
  __shared__ double bS;

  float wm = m;
  #pragma unroll
  for (int off = 32; off; off >>= 1) wm = fmaxf(wm, __shfl_xor(wm, off));
  const int wid = tid >> 6;
  if ((tid & 63) == 0) lsm[wid] = wm;
  __syncthreads();
  if (tid == 0) bM = fmaxf(fmaxf(lsm[0], lsm[1]), fmaxf(lsm[2], lsm[3]));
  __syncthreads();
  const float M = bM;

  double s2 = s * exp((double)m - (double)M);
  #pragma unroll
  for (int off = 32; off; off >>= 1) s2 += __shfl_xor(s2, off);
  if ((tid & 63) == 0) lss[wid] = s2;
  __syncthreads();
  if (tid == 0) bS = lss[0] + lss[1] + lss[2] + lss[3];
  __syncthreads();
  const double S = bS;

  if (tid < NT) {
    const int c = tgt[tid];
    const double p = exp((double)x[c] - (double)M) / S;
    const float cv = 1.0f - (float)p;
    C[(size_t)tid * NQ + row]    = cv;
    Ccol[(size_t)row * NT + tid] = cv;
  }
}

// ---------------------------------------------------------------------------
// Kernel B1: per (row, 1024-part) top-256 sorted ascending by (cost_bits, j).
// ---------------------------------------------------------------------------
__global__ __launch_bounds__(256) void select_part(
    const float* __restrict__ C, unsigned long long* __restrict__ S1)
{
  __shared__ unsigned long long key[1024];
  const int part = blockIdx.x, t = blockIdx.y, tid = threadIdx.x;
  const float* crow = C + (size_t)t * NQ + part * 1024;
  for (int i = tid; i < 1024; i += 256)
    key[i] = ((unsigned long long)__float_as_uint(crow[i]) << 32)
           | (unsigned)(part * 1024 + i);

  for (int k = 2; k <= 256; k <<= 1)
    for (int jj = k >> 1; jj > 0; jj >>= 1) {
      __syncthreads();
      for (int w = tid; w < 512; w += 256) {
        const int i1 = ((w & ~(jj - 1)) << 1) | (w & (jj - 1));
        const int i2 = i1 | jj;
        const bool up = (((i1 & 255) & k) == 0);
        const unsigned long long a = key[i1], b = key[i2];
        if ((a > b) == up) { key[i1] = b; key[i2] = a; }
      }
    }

  for (int step = 1; step < 4; step <<= 1) {
    const int npairs = 2 / step;
    __syncthreads();
    for (int w = tid; w < npairs * 256; w += 256) {
      const int p = w >> 8, i = w & 255;
      const int a = ((p * 2 * step) << 8) + i;
      const int b = ((p * 2 * step + step) << 8) + 255 - i;
      const unsigned long long ka = key[a], kb = key[b];
      if (ka > kb) key[a] = kb;
    }
    for (int jj = 128; jj > 0; jj >>= 1) {
      __syncthreads();
      for (int w = tid; w < npairs * 128; w += 256) {
        const int p = w >> 7, q = w & 127;
        const int base = (p * 2 * step) << 8;
        const int i1 = base + (((q & ~(jj - 1)) << 1) | (q & (jj - 1)));
        const int i2 = i1 | jj;
        const unsigned long long a = key[i1], b = key[i2];
        if (a > b) { key[i1] = b; key[i2] = a; }
      }
    }
  }
  __syncthreads();
  S1[((size_t)t * 8 + part) * 256 + tid] = key[tid];
}

// ---------------------------------------------------------------------------
// Kernel B2: merge 8 sorted top-256 lists -> top-256 per row (3 rounds).
// ---------------------------------------------------------------------------
__global__ __launch_bounds__(256) void select_merge(
    const unsigned long long* __restrict__ S1, unsigned long long* __restrict__ S)
{
  __shared__ unsigned long long key[2048];
  const int t = blockIdx.x, tid = threadIdx.x;
  for (int i = tid; i < 2048; i += 256) key[i] = S1[(size_t)t * 2048 + i];

  for (int step = 1; step < 8; step <<= 1) {
    const int npairs = 4 / step;
    __syncthreads();
    for (int w = tid; w < npairs * 256; w += 256) {
      const int p = w >> 8, i = w & 255;
      const int a = ((p * 2 * step) << 8) + i;
      const int b = ((p * 2 * step + step) << 8) + 255 - i;
      const unsigned long long ka = key[a], kb = key[b];
      if (ka > kb) key[a] = kb;
    }
    for (int jj = 128; jj > 0; jj >>= 1) {
      __syncthreads();
      for (int w = tid; w < npairs * 128; w += 256) {
        const int p = w >> 7, q = w & 127;
        const int base = (p * 2 * step) << 8;
        const int i1 = base + (((q & ~(jj - 1)) << 1) | (q & (jj - 1)));
        const int i2 = i1 | jj;
        const unsigned long long a = key[i1], b = key[i2];
        if (a > b) { key[i1] = b; key[i2] = a; }
      }
    }
  }
  __syncthreads();
  S[(size_t)t * SROW + tid] = key[tid];
}

// --------------------------- readlane helpers ------------------------------
__device__ __forceinline__ int rl_i32(int v, int l) {
  return __builtin_amdgcn_readlane(v, l);
}
__device__ __forceinline__ double rl_f64(double v, int l) {
  union { double d; int i[2]; } a; a.d = v;
  union { int i[2]; double d; } r;
  r.i[0] = __builtin_amdgcn_readlane(a.i[0], l);
  r.i[1] = __builtin_amdgcn_readlane(a.i[1], l);
  return r.d;
}
__device__ __forceinline__ unsigned long long rl_u64(unsigned long long v, int l) {
  union { unsigned long long q; int i[2]; } a; a.q = v;
  union { int i[2]; unsigned long long q; } r;
  r.i[0] = __builtin_amdgcn_readlane(a.i[0], l);
  r.i[1] = __builtin_amdgcn_readlane(a.i[1], l);
  return r.q;
}

// DPP value-only f64 min step (no NaNs in this kernel; zeros sign-safe).
template <int CTRL>
__device__ __forceinline__ double dpp_min_f64(double cr) {
  union { double d; int i[2]; } a, r;
  a.d = cr;
  r.i[0] = __builtin_amdgcn_update_dpp(0, a.i[0], CTRL, 0xF, 0xF, true);
  r.i[1] = __builtin_amdgcn_update_dpp(0, a.i[1], CTRL, 0xF, 0xF, true);
  return fmin(cr, r.d);
}

// ---------------------------------------------------------------------------
// Kernel C: exact JV LSAP, single wave, barrier-free.
// vs R8: (1) decision restructured so the winning-column index (acol
// readlane / min-acol scan) is only computed on an exact f64 tie with the
// U-side (rare) — hot path is two f64 compares + ctz + arow readlane;
// (2) speculative Ccol prefetch: sink == ub_j at termination, so the column
// loads issued whenever ub_j changes are exactly the sink column by augment
// time — removes the exposed L2/L3 latency of the slot fill.
// Decision semantics identical to the verified R2..R8 solver.
// ---------------------------------------------------------------------------
__global__ __launch_bounds__(64) void lsap_solve(
    const float* __restrict__ Ccol, const unsigned long long* __restrict__ S,
    int* __restrict__ outi)
{
  const int lane = threadIdx.x;

  __shared__ float  Clds[NT][SLOTC];            // 64 KB, [row][(slot+row)&127]
  __shared__ double du[NT];                     // dual-delta routing
  __shared__ unsigned long long abm[NQ / 64];   // assigned bitmap (probe-only)
  __shared__ short col4row_s[NT];               // staging for the final sort

  int    acolA = -1, acolB = -1;     // column of slot (A: slot=lane, B: 64+lane)
  int    arowA = -1, arowB = -1;     // row4col[col]
  int    apathA = -1, apathB = -1;   // path[col]
  double avA = 0.0, avB = 0.0;       // v[col]
  double ashA = 0.0, ashB = 0.0;     // shortest[col]
  double afzA = 0.0, afzB = 0.0;     // shortest frozen at selection
  bool   ascA = false, ascB = false; // SC[col]
  int    nA = 0;

  // lane L owns rows L and 64+L:
  double uA = 0.0, uB = 0.0;                       // u[row]
  int    c4rA = -1, c4rB = -1;                     // col4row[row]
  unsigned long long candA, candB, candA2, candB2; // 1st/2nd unassigned keys
  int    curA, curB, curA2, curB2;                 // their sorted positions

  abm[lane] = 0ull;  abm[64 + lane] = 0ull;
  candA  = S[(size_t)lane * SROW];
  candA2 = S[(size_t)lane * SROW + 1];
  candB  = S[(size_t)(64 + lane) * SROW];
  candB2 = S[(size_t)(64 + lane) * SROW + 1];
  curA = 0; curA2 = 1; curB = 0; curB2 = 1;

  for (int cur = 0; cur < NT; ++cur) {
    ashA = INFINITY; ashB = INFINITY; ascA = false; ascB = false;
    double ub_r = INFINITY; int ub_j = 0x7fffffff, ub_i = -1;
    int icur = cur; double minval = 0.0;
    int sink = -1, sinkpath = -1;
    float pf0 = 0.f, pf1 = 0.f;    // speculative sink-column prefetch regs

    while (sink < 0) {
      const double u_i = (icur < 64) ? rl_f64(uA, icur) : rl_f64(uB, icur - 64);
      const bool actA = (lane < nA) && !ascA;
      const bool actB = (64 + lane < nA) && !ascB;
      float cA = 0.f, cB = 0.f;
      if (actA) cA = Clds[icur][(lane + icur) & 127];
      if (actB) cB = Clds[icur][(64 + lane + icur) & 127];

      // --- U-side: register-cached first-unassigned sorted candidate
      unsigned long long kk = (icur < 64) ? rl_u64(candA, icur)
                                          : rl_u64(candB, icur - 64);
      if (kk == 0ull) {   // probe the sorted row (rare: both cache levels dead)
        int pos = (icur < 64) ? rl_i32(curA, icur) : rl_i32(curB, icur - 64);
        unsigned long long kk2 = 0ull; int pos2 = pos;
        for (;;) {
          const unsigned long long k = S[(size_t)icur * SROW + pos + lane];
          const int j = (int)(k & 0xffffffffu);
          const bool asg = (abm[j >> 6] >> (j & 63)) & 1ull;
          const unsigned long long bal = __ballot(!asg);
          if (bal) {
            const int f = __builtin_ctzll(bal);
            kk = rl_u64(k, f);
            const unsigned long long bal2 = bal & (bal - 1);
            if (bal2) {
              const int f2 = __builtin_ctzll(bal2);
              kk2  = rl_u64(k, f2);
              pos2 = pos + f2;
            }
            pos += f;
            break;
          }
          pos += 64;
        }
        if (lane == (icur & 63)) {
          if (icur < 64) { candA = kk; curA = pos; candA2 = kk2; curA2 = pos2; }
          else           { candB = kk; curB = pos; candB2 = kk2; curB2 = pos2; }
        }
      }
      bool ubchg = false;
      {
        const int    jU = (int)(kk & 0xffffffffu);
        const double cU = (double)__uint_as_float((unsigned)(kk >> 32));
        const double rU = ((minval + cU) - u_i) - 0.0;   // v[j]==0 on U
        if (rU < ub_r || (rU == ub_r && jU < ub_j)) {
          ub_r = rU; ub_j = jU; ub_i = icur; ubchg = true;
        }
      }
      // speculative prefetch of the (current) U-best column; at termination
      // sink == ub_j, so the last-issued loads are exactly the sink column.
      if (ubchg) {
        pf0 = Ccol[(size_t)ub_j * NT + lane];
        pf1 = Ccol[(size_t)ub_j * NT + 64 + lane];
      }

      // --- A-side: update shortest over unscanned assigned columns
      if (actA) {
        const double r = ((minval + (double)cA) - u_i) - avA;
        if (r < ashA) { ashA = r; apathA = icur; }
      }
      if (actB) {
        const double r = ((minval + (double)cB) - u_i) - avB;
        if (r < ashB) { ashB = r; apathB = icur; }
      }
      // value-only min: per-lane pair, DPP within 16-groups, readlane across
      double cr = actA ? ashA : INFINITY;
      if (actB) cr = fmin(cr, ashB);
      cr = dpp_min_f64<0xB1>(cr);    // quad_perm(1,0,3,2)  == xor 1
      cr = dpp_min_f64<0x4E>(cr);    // quad_perm(2,3,0,1)  == xor 2
      cr = dpp_min_f64<0x141>(cr);   // row_half_mirror     == xor 7
      cr = dpp_min_f64<0x140>(cr);   // row_mirror          == xor 15
      cr = fmin(fmin(rl_f64(cr, 0), rl_f64(cr, 16)),
                fmin(rl_f64(cr, 32), rl_f64(cr, 48)));

      // --- decision: value compares first; column index only on exact tie
      const bool mA = actA && (ashA == cr);
      const bool mB = actB && (ashB == cr);
      const unsigned long long balA = __ballot(mA);
      const unsigned long long balB = __ballot(mB);
      const unsigned long long bal  = balA | balB;
      bool awin;
      int ln = -1, isB = 0;
      if (cr < ub_r) {
        const bool multi = (((balA & balB) | (bal & (bal - 1))) != 0ull);
        if (!multi) {                       // hot path: unique achiever
          ln  = (int)__builtin_ctzll(bal);
          isB = (balA == 0ull);
        } else {                            // rare: min-acol among achievers
          int cj = 0x7fffffff;
          unsigned long long ba = balA;
          while (ba) {
            const int l = (int)__builtin_ctzll(ba); ba &= ba - 1;
            const int c = rl_i32(acolA, l);
            if (c < cj) { cj = c; ln = l; isB = 0; }
          }
          unsigned long long bb = balB;
          while (bb) {
            const int l = (int)__builtin_ctzll(bb); bb &= bb - 1;
            const int c = rl_i32(acolB, l);
            if (c < cj) { cj = c; ln = l; isB = 1; }
          }
        }
        awin = true;
      } else if (cr > ub_r) {
        awin = false;
      } else {                              // exact f64 tie (measure-zero)
        int cj = 0x7fffffff;
        unsigned long long ba = balA;
        while (ba) {
          const int l = (int)__builtin_ctzll(ba); ba &= ba - 1;
          const int c = rl_i32(acolA, l);
          if (c < cj) { cj = c; ln = l; isB = 0; }
        }
        unsigned long long bb = balB;
        while (bb) {
          const int l = (int)__builtin_ctzll(bb); bb &= bb - 1;
          const int c = rl_i32(acolB, l);
          if (c < cj) { cj = c; ln = l; isB = 1; }
        }
        awin = (cj < ub_j);
      }

      if (awin) {
        minval = cr;
        if (lane == ln) {
          if (isB) { ascB = true; afzB = cr; }
          else     { ascA = true; afzA = cr; }
        }
        icur = isB ? rl_i32(arowB, ln) : rl_i32(arowA, ln);
      } else {
        minval = ub_r;
        sink = ub_j; sinkpath = ub_i;
      }
    }

    const int nAold = nA;

    // --- dual updates: write deltas; read-back deferred past the walk
    du[lane] = 0.0; du[64 + lane] = 0.0;
    if (ascA) { du[arowA] = minval - afzA; avA -= (minval - afzA); }
    if (ascB) { du[arowB] = minval - afzB; avB -= (minval - afzB); }

    // --- augment along the alternating path
    {
      int j = sink, i = sinkpath;
      if (lane == (nAold & 63)) {            // append sink as new slot
        if (nAold < 64) { acolA = sink; avA = 0.0; arowA = i; }
        else            { acolB = sink; avB = 0.0; arowB = i; }
      }
      if (lane == 0) abm[sink >> 6] |= 1ull << (sink & 63);
      nA = nAold + 1;
      for (;;) {
        const int jn = (i < 64) ? rl_i32(c4rA, i) : rl_i32(c4rB, i - 64);
        if (lane == (i & 63)) { if (i < 64) c4rA = j; else c4rB = j; }
        if (i == cur) break;
        j = jn;
        const bool hA = (acolA == j);
        const bool hB = (acolB == j);
        const unsigned long long bal = __ballot(hA || hB);
        const int ln2 = (int)__builtin_ctzll(bal);
        const int isB2 = rl_i32(hB ? 1 : 0, ln2);
        const int ni = isB2 ? rl_i32(apathB, ln2) : rl_i32(apathA, ln2);
        if (lane == ln2) { if (isB2) arowB = ni; else arowA = ni; }
        i = ni;
      }
    }

    // --- deferred dual read-back (du stores have drained under the walk)
    uA += du[lane];
    uB += du[64 + lane];
    if (lane == (cur & 63)) { if (cur < 64) uA += minval; else uB += minval; }

    // --- cand invalidation with register promotion (exact)
    if ((int)(candA2 & 0xffffffffu) == sink) candA2 = 0ull;
    if ((int)(candB2 & 0xffffffffu) == sink) candB2 = 0ull;
    if ((int)(candA  & 0xffffffffu) == sink) {
      candA = candA2; curA = curA2; candA2 = 0ull;
    }
    if ((int)(candB  & 0xffffffffu) == sink) {
      candB = candB2; curB = curB2; candB2 = 0ull;
    }

    // --- land the prefetched sink column into swizzled Clds (conflict-free)
    Clds[lane][(nAold + lane) & 127]           = pf0;
    Clds[64 + lane][(nAold + 64 + lane) & 127] = pf1;
  }

  // output: rows = col4row (query idx), cols = arange(NT), sorted by query idx
  col4row_s[lane]      = (short)c4rA;
  col4row_s[64 + lane] = (short)c4rB;
  for (int t = lane; t < NT; t += 64) {
    const int q = col4row_s[t];
    int rank = 0;
    for (int k = 0; k < NT; ++k) rank += (col4row_s[k] < q);
    outi[rank]      = q;
    outi[NT + rank] = t;
  }
}

extern "C" void kernel_launch(void* const* d_in, const int* in_sizes, int n_in,
                              void* d_out, int out_size, void* d_ws, size_t ws_size,
                              hipStream_t stream) {
  (void)in_sizes; (void)n_in; (void)out_size; (void)ws_size;
  const float* outputs = (const float*)d_in[0];
  const int*   targets = (const int*)d_in[1];
  char* ws = (char*)d_ws;
  float* C    = (float*)ws;                                  // 4 MB
  float* Ccol = (float*)(ws + (size_t)NT * NQ * 4);          // 4 MB
  unsigned long long* S1 =
      (unsigned long long*)(ws + (size_t)NT * NQ * 8);       // 2 MB
  unsigned long long* S =
      (unsigned long long*)(ws + (size_t)NT * NQ * 8 + (size_t)NT * 8 * 256 * 8);
  int* out = (int*)d_out;

  build_cost<<<NQ, 256, 0, stream>>>(outputs, targets, C, Ccol);
  select_part<<<dim3(8, NT), 256, 0, stream>>>(C, S1);
  select_merge<<<NT, 256, 0, stream>>>(S1, S);
  lsap_solve<<<1, 64, 0, stream>>>(Ccol, S, out);
}